// Round 4
// baseline (559.339 us; speedup 1.0000x reference)
//
#include <hip/hip_runtime.h>
#include <math.h>

#define BATCH 256
#define ISZ 256
#define H 512
#define BH (BATCH * H)       // 131072
#define CLIPV 2.0f

#define BT 64
#define KT 32
#define LDSP (BT + 4)

typedef float f4_t __attribute__((ext_vector_type(4)));

__device__ __forceinline__ float sigmoidf_(float x) { return 1.0f / (1.0f + expf(-x)); }
__device__ __forceinline__ void nt_store4(f4_t* p, f4_t v) { __builtin_nontemporal_store(v, p); }

// ---------------- K1: 8 chunk-GEMMs x 32 tiles (64x64), outputs pre[8][256][512] ----------------
//   ch0: x@x2f_w^T (+f biases) K=256 | ch1: h0@h2f_w^T K=512
//   ch2: x@x2i_w^T (+i biases) K=256 | ch3: h0@h2i_w^T K=512
//   ch4: x@x2o_w^T (+o biases) K=256 | ch5: h0@h2o_w^T K=512
//   ch6: x@x2c_w^T (+x2c_b)    K=256 | ch7: h0@w (n-major) K=512
__global__ __launch_bounds__(256) void gemms(
    const float* __restrict__ x, const float* __restrict__ h0,
    const float* __restrict__ x2f_w, const float* __restrict__ x2f_b,
    const float* __restrict__ h2f_w, const float* __restrict__ h2f_b,
    const float* __restrict__ x2i_w, const float* __restrict__ x2i_b,
    const float* __restrict__ h2i_w, const float* __restrict__ h2i_b,
    const float* __restrict__ x2o_w, const float* __restrict__ x2o_b,
    const float* __restrict__ h2o_w, const float* __restrict__ h2o_b,
    const float* __restrict__ x2c_w, const float* __restrict__ x2c_b,
    const float* __restrict__ w,
    float* __restrict__ pre)
{
  __shared__ __align__(16) float As[KT][LDSP];
  __shared__ __align__(16) float Bs[KT][LDSP];

  const int bid = blockIdx.x;
  const int t   = threadIdx.x;
  const int ch  = bid >> 5;
  const int rem = bid & 31;
  const int n0  = (rem & 7) * BT;
  const int m0  = (rem >> 3) * BT;
  const int tx = t & 15, ty = t >> 4;

  const float* A; const float* Bm; int lda, K; bool kmajor = true;
  const float* b1 = nullptr; const float* b2 = nullptr;
  switch (ch) {
    case 0: A = x;  lda = ISZ; K = ISZ; Bm = x2f_w; b1 = x2f_b; b2 = h2f_b; break;
    case 1: A = h0; lda = H;   K = H;   Bm = h2f_w; break;
    case 2: A = x;  lda = ISZ; K = ISZ; Bm = x2i_w; b1 = x2i_b; b2 = h2i_b; break;
    case 3: A = h0; lda = H;   K = H;   Bm = h2i_w; break;
    case 4: A = x;  lda = ISZ; K = ISZ; Bm = x2o_w; b1 = x2o_b; b2 = h2o_b; break;
    case 5: A = h0; lda = H;   K = H;   Bm = h2o_w; break;
    case 6: A = x;  lda = ISZ; K = ISZ; Bm = x2c_w; b1 = x2c_b; break;
    default: A = h0; lda = H;  K = H;   Bm = w; kmajor = false; break;
  }

  float acc[4][4] = {{0.0f}};
  for (int kk0 = 0; kk0 < K; kk0 += KT) {
    #pragma unroll
    for (int i = 0; i < 2; ++i) {
      int l = i * 256 + t;
      int r = l >> 3, c = l & 7;
      float4 v = *(const float4*)&A[(size_t)(m0 + r) * lda + kk0 + c * 4];
      As[c * 4 + 0][r] = v.x; As[c * 4 + 1][r] = v.y;
      As[c * 4 + 2][r] = v.z; As[c * 4 + 3][r] = v.w;
    }
    if (kmajor) {
      #pragma unroll
      for (int i = 0; i < 2; ++i) {
        int l = i * 256 + t;
        int n = l >> 3, c = l & 7;
        float4 v = *(const float4*)&Bm[(size_t)(n0 + n) * K + kk0 + c * 4];
        Bs[c * 4 + 0][n] = v.x; Bs[c * 4 + 1][n] = v.y;
        Bs[c * 4 + 2][n] = v.z; Bs[c * 4 + 3][n] = v.w;
      }
    } else {
      #pragma unroll
      for (int i = 0; i < 2; ++i) {
        int l = i * 256 + t;
        int j = l >> 4, c = l & 15;
        float4 v = *(const float4*)&Bm[(size_t)(kk0 + j) * H + n0 + c * 4];
        *(float4*)&Bs[j][c * 4] = v;
      }
    }
    __syncthreads();
    #pragma unroll
    for (int j = 0; j < KT; ++j) {
      float4 a  = *(const float4*)&As[j][ty * 4];
      float4 bv = *(const float4*)&Bs[j][tx * 4];
      float av[4] = {a.x, a.y, a.z, a.w};
      float bw[4] = {bv.x, bv.y, bv.z, bv.w};
      #pragma unroll
      for (int r = 0; r < 4; ++r)
        #pragma unroll
        for (int c = 0; c < 4; ++c)
          acc[r][c] += av[r] * bw[c];
    }
    __syncthreads();
  }

  float bias[4];
  #pragma unroll
  for (int c = 0; c < 4; ++c) {
    int n = n0 + tx * 4 + c;
    float bv = 0.0f;
    if (b1) bv += b1[n];
    if (b2) bv += b2[n];
    bias[c] = bv;
  }
  float* outc = pre + (size_t)ch * BH;
  #pragma unroll
  for (int r = 0; r < 4; ++r) {
    int m = m0 + ty * 4 + r;
    float4 o;
    o.x = acc[r][0] + bias[0];
    o.y = acc[r][1] + bias[1];
    o.z = acc[r][2] + bias[2];
    o.w = acc[r][3] + bias[3];
    *(float4*)&outc[(size_t)m * H + n0 + tx * 4] = o;
  }
}

// ---------------- K2: one block per batch — einsum + gates + mod + hebb update ----------------
// Block-local chain (no cross-batch deps): phase A streams this batch's 1MB hebb
// region (allocates L3), LDS holds hb/eta, phase B re-reads the SAME region in
// reverse row order (L3-hot) and nt-stores hebb_new (no-allocate, no pollution).
__global__ __launch_bounds__(512) void batch_fused(
    const float* __restrict__ pre, const float* __restrict__ hebb,
    const float* __restrict__ h0, const float* __restrict__ c0,
    const float* __restrict__ alpha,
    const float* __restrict__ h2mod_w, const float* __restrict__ h2mod_b,
    const float* __restrict__ mfo_w, const float* __restrict__ mfo_b,
    float* __restrict__ out)
{
  __shared__ float h0s[H];
  __shared__ f4_t redv[3][128];
  __shared__ float hbs[H];
  __shared__ float red[8];
  __shared__ float mm;
  __shared__ f4_t eta4[128];

  const int b   = blockIdx.x;
  const int t   = threadIdx.x;
  const int col = t & 127;     // f4 column
  const int rg  = t >> 7;      // row-group 0..3 (128 rows each)

  h0s[t] = h0[b * H + t];
  __syncthreads();

  // ---- Phase A: hb[k] = sum_h h0[h] * hebb[b,h,k]
  const f4_t* hb4 = (const f4_t*)hebb + ((size_t)b * H + rg * 128) * 128 + col;
  f4_t acc = {0.f, 0.f, 0.f, 0.f};
  #pragma unroll 8
  for (int h = 0; h < 128; ++h)
    acc += h0s[rg * 128 + h] * hb4[(size_t)h * 128];
  if (rg) redv[rg - 1][col] = acc;
  __syncthreads();
  if (rg == 0) {
    acc += redv[0][col]; acc += redv[1][col]; acc += redv[2][col];
    *(f4_t*)&hbs[col * 4] = acc;
  }
  __syncthreads();

  // ---- Gates / cell / hactiv for k = t
  const size_t idx = (size_t)b * H + t;
  float h2c  = pre[(size_t)7 * BH + idx] + alpha[t] * hbs[t];
  float itcv = tanhf(pre[(size_t)6 * BH + idx] + h2c);
  float f = sigmoidf_(pre[idx]                  + pre[(size_t)1 * BH + idx]);
  float i = sigmoidf_(pre[(size_t)2 * BH + idx] + pre[(size_t)3 * BH + idx]);
  float o = sigmoidf_(pre[(size_t)4 * BH + idx] + pre[(size_t)5 * BH + idx]);
  float cell = f * c0[idx] + i * itcv;
  float hav  = o * tanhf(cell);
  out[idx] = hav;
  out[BH + idx] = cell;

  // ---- m = tanh(hactiv . h2mod_w + b), eta[k] = (m*mfo_w[k]+mfo_b[k])*itc[k]
  float s = hav * h2mod_w[t];
  #pragma unroll
  for (int off = 32; off > 0; off >>= 1) s += __shfl_down(s, off, 64);
  if ((t & 63) == 0) red[t >> 6] = s;
  __syncthreads();
  if (t == 0)
    mm = tanhf(red[0] + red[1] + red[2] + red[3] +
               red[4] + red[5] + red[6] + red[7] + h2mod_b[0]);
  __syncthreads();
  ((float*)eta4)[t] = (mm * mfo_w[t] + mfo_b[t]) * itcv;
  __syncthreads();

  // ---- Phase B: hebb_new = clip(hebb + h0[h]*eta[k]), reverse rows (L3-hot first)
  f4_t e = eta4[col];
  f4_t* dst = (f4_t*)out + (size_t)(2 * BH / 4) +
              ((size_t)b * H + rg * 128) * 128 + col;
  #pragma unroll 8
  for (int h = 127; h >= 0; --h) {
    float sh = h0s[rg * 128 + h];
    f4_t v = hb4[(size_t)h * 128];
    f4_t r;
    r.x = fminf(fmaxf(v.x + sh * e.x, -CLIPV), CLIPV);
    r.y = fminf(fmaxf(v.y + sh * e.y, -CLIPV), CLIPV);
    r.z = fminf(fmaxf(v.z + sh * e.z, -CLIPV), CLIPV);
    r.w = fminf(fmaxf(v.w + sh * e.w, -CLIPV), CLIPV);
    nt_store4(dst + (size_t)h * 128, r);
  }
}

extern "C" void kernel_launch(void* const* d_in, const int* in_sizes, int n_in,
                              void* d_out, int out_size, void* d_ws, size_t ws_size,
                              hipStream_t stream) {
  const float* x       = (const float*)d_in[0];
  const float* h0      = (const float*)d_in[1];
  const float* c0      = (const float*)d_in[2];
  const float* hebb    = (const float*)d_in[3];
  const float* w       = (const float*)d_in[4];
  const float* alpha   = (const float*)d_in[5];
  const float* h2f_w   = (const float*)d_in[6];
  const float* h2f_b   = (const float*)d_in[7];
  const float* h2i_w   = (const float*)d_in[8];
  const float* h2i_b   = (const float*)d_in[9];
  const float* h2o_w   = (const float*)d_in[10];
  const float* h2o_b   = (const float*)d_in[11];
  const float* x2f_w   = (const float*)d_in[12];
  const float* x2f_b   = (const float*)d_in[13];
  const float* x2i_w   = (const float*)d_in[14];
  const float* x2i_b   = (const float*)d_in[15];
  const float* x2o_w   = (const float*)d_in[16];
  const float* x2o_b   = (const float*)d_in[17];
  const float* x2c_w   = (const float*)d_in[18];
  const float* x2c_b   = (const float*)d_in[19];
  const float* h2mod_w = (const float*)d_in[20];
  const float* h2mod_b = (const float*)d_in[21];
  const float* mfo_w   = (const float*)d_in[22];
  const float* mfo_b   = (const float*)d_in[23];

  float* out = (float*)d_out;
  float* pre = (float*)d_ws;                  // 8 * 131072 floats (4.19 MB)

  gemms<<<256, 256, 0, stream>>>(
      x, h0, x2f_w, x2f_b, h2f_w, h2f_b, x2i_w, x2i_b, h2i_w, h2i_b,
      x2o_w, x2o_b, h2o_w, h2o_b, x2c_w, x2c_b, w, pre);

  batch_fused<<<BATCH, 512, 0, stream>>>(
      pre, hebb, h0, c0, alpha, h2mod_w, h2mod_b, mfo_w, mfo_b, out);
}